// Round 6
// baseline (919.142 us; speedup 1.0000x reference)
//
#include <hip/hip_runtime.h>
#include <hip/hip_bf16.h>
#include <math.h>

// LGCN layer, coarse-bucket counting sort (write-amplification fix):
//   agg = segsum(atten*src) @ W_rel          (W_rel commutes out of the sum)
//   att_logit = s1[src] + s2[dst]            (lin_w splits into two per-node dots)
// R5: fine 50K-bucket scatter had 8x write amplification (WRITE_SIZE 103MB for
//     a 12.8MB ebuf: random 8B stores, one per 64B line). Now: coarse buckets
//     of NB=64 dst nodes (C=782), LDS-staged per-block reservation -> each
//     block writes ~84B contiguous runs per bucket. Reducer = one block per
//     bucket, LDS f32 accumulate tile + fused matvec/tanh epilogue. Fine
//     histogram + 3-kernel scan deleted (7 launches -> 5).

#define D 64
#define SHIFT 6
#define NB (1 << SHIFT)          // dst nodes per coarse bucket
#define CMAX 1024                // max buckets (requires N <= 65536)
#define CHUNK 8192               // edges per block in hist/scatter

// ---------------- kernel 1: per-node attention scalars + zero ghist ---------
__global__ __launch_bounds__(256) void precompute_att(
    const float* __restrict__ feat, const float* __restrict__ lin_w,
    const float* __restrict__ lin_b, float* __restrict__ s1,
    float* __restrict__ s2, int* __restrict__ ghist, int C, int N) {
  const int gt = blockIdx.x * 256 + threadIdx.x;
  for (int i = gt; i < C; i += gridDim.x * 256) ghist[i] = 0;

  const int lane = threadIdx.x & 63;
  const int wid  = (blockIdx.x * blockDim.x + threadIdx.x) >> 6;
  const int nw   = (gridDim.x * blockDim.x) >> 6;
  const float w1 = lin_w[lane];
  const float w2 = lin_w[64 + lane];
  const float b  = lin_b[0];
  for (int i = wid; i < N; i += nw) {
    const float f = feat[(size_t)i * D + lane];
    float v1 = f * w1;
    float v2 = f * w2;
    #pragma unroll
    for (int off = 32; off > 0; off >>= 1) {
      v1 += __shfl_down(v1, off, 64);
      v2 += __shfl_down(v2, off, 64);
    }
    if (lane == 0) {
      s1[i] = v1 + b;   // fold bias into s1
      s2[i] = v2;
    }
  }
}

// ---------------- kernel 2: coarse histogram (LDS-staged) ----------------
__global__ __launch_bounds__(256) void coarse_hist(
    const int* __restrict__ edst, int* __restrict__ ghist, int E, int C) {
  __shared__ int h[CMAX];
  for (int i = threadIdx.x; i < C; i += 256) h[i] = 0;
  __syncthreads();
  const int E4 = E >> 2;
  const int4* edst4 = (const int4*)edst;
  const int b4 = blockIdx.x * (CHUNK >> 2);
  #pragma unroll
  for (int k = 0; k < 8; ++k) {
    const int i4 = b4 + threadIdx.x + 256 * k;
    if (i4 < E4) {
      const int4 d = edst4[i4];
      atomicAdd(&h[d.x >> SHIFT], 1);
      atomicAdd(&h[d.y >> SHIFT], 1);
      atomicAdd(&h[d.z >> SHIFT], 1);
      atomicAdd(&h[d.w >> SHIFT], 1);
    }
  }
  if (blockIdx.x == 0 && threadIdx.x == 0) {      // E%4 tail
    for (int e = E4 << 2; e < E; ++e) atomicAdd(&h[edst[e] >> SHIFT], 1);
  }
  __syncthreads();
  for (int i = threadIdx.x; i < C; i += 256) {
    const int v = h[i];
    if (v) atomicAdd(&ghist[i], v);
  }
}

// ---------------- kernel 3: exclusive scan of C<=1024 bucket counts --------
__global__ __launch_bounds__(1024) void scan_coarse(
    const int* __restrict__ ghist, int* __restrict__ bstart,
    int* __restrict__ gcur, int C) {
  __shared__ int tot[1024];
  const int t = threadIdx.x;
  const int v = (t < C) ? ghist[t] : 0;
  tot[t] = v;
  __syncthreads();
  for (int off = 1; off < 1024; off <<= 1) {
    int u = tot[t] + ((t >= off) ? tot[t - off] : 0);
    __syncthreads();
    tot[t] = u;
    __syncthreads();
  }
  if (t < C) {
    bstart[t] = tot[t] - v;
    gcur[t]   = tot[t] - v;
  }
}

// ---------------- kernel 4: coarse scatter, LDS-staged runs ----------------
// Each block reserves one contiguous run per bucket (returning global atomic
// on gcur) and writes its chunk's edges grouped -> dense ~84B runs, no 8x
// line-writeback amplification. Entry: x = src | (dstlocal<<26), y = att f32.
__global__ __launch_bounds__(256) void coarse_scatter(
    const int* __restrict__ esrc, const int* __restrict__ edst,
    const float* __restrict__ s1, const float* __restrict__ s2,
    int* __restrict__ gcur, uint2* __restrict__ ebuf, int E, int C) {
  __shared__ int h[CMAX];
  __shared__ int cur[CMAX];
  __shared__ int bl[CMAX];
  for (int i = threadIdx.x; i < C; i += 256) h[i] = 0;
  __syncthreads();
  const int E4 = E >> 2;
  const int4* edst4 = (const int4*)edst;
  const int4* esrc4 = (const int4*)esrc;
  const int b4 = blockIdx.x * (CHUNK >> 2);
  const bool tail0 = (blockIdx.x == 0) && (threadIdx.x == 0);

  #pragma unroll
  for (int k = 0; k < 8; ++k) {
    const int i4 = b4 + threadIdx.x + 256 * k;
    if (i4 < E4) {
      const int4 d = edst4[i4];
      atomicAdd(&h[d.x >> SHIFT], 1);
      atomicAdd(&h[d.y >> SHIFT], 1);
      atomicAdd(&h[d.z >> SHIFT], 1);
      atomicAdd(&h[d.w >> SHIFT], 1);
    }
  }
  if (tail0) for (int e = E4 << 2; e < E; ++e) atomicAdd(&h[edst[e] >> SHIFT], 1);
  __syncthreads();
  for (int i = threadIdx.x; i < C; i += 256) {
    const int v = h[i];
    bl[i] = v ? atomicAdd(&gcur[i], v) : 0;
    cur[i] = 0;
  }
  __syncthreads();

  #pragma unroll
  for (int k = 0; k < 8; ++k) {
    const int i4 = b4 + threadIdx.x + 256 * k;
    if (i4 < E4) {
      const int4 s = esrc4[i4];
      const int4 d = edst4[i4];
      const int ss[4] = {s.x, s.y, s.z, s.w};
      const int dd[4] = {d.x, d.y, d.z, d.w};
      float a1[4], a2[4];
      #pragma unroll
      for (int j = 0; j < 4; ++j) a1[j] = s1[ss[j]];   // independent gathers
      #pragma unroll
      for (int j = 0; j < 4; ++j) a2[j] = s2[dd[j]];
      #pragma unroll
      for (int j = 0; j < 4; ++j) {
        const float a = 1.0f / (1.0f + __expf(-fmaxf(a1[j] + a2[j], 0.0f)));
        const int bk = dd[j] >> SHIFT;
        const int r  = atomicAdd(&cur[bk], 1);
        ebuf[bl[bk] + r] =
            make_uint2((unsigned)ss[j] | ((unsigned)(dd[j] & (NB - 1)) << 26),
                       __float_as_uint(a));
      }
    }
  }
  if (tail0) {
    for (int e = E4 << 2; e < E; ++e) {
      const int sj = esrc[e], dj = edst[e];
      const float a = 1.0f / (1.0f + __expf(-fmaxf(s1[sj] + s2[dj], 0.0f)));
      const int bk = dj >> SHIFT;
      const int r  = atomicAdd(&cur[bk], 1);
      ebuf[bl[bk] + r] =
          make_uint2((unsigned)sj | ((unsigned)(dj & (NB - 1)) << 26),
                     __float_as_uint(a));
    }
  }
}

// ---------------- kernel 5: per-bucket LDS accumulate + finalize -----------
__global__ __launch_bounds__(256) void bucket_reduce(
    const float* __restrict__ feat, const float* __restrict__ norm,
    const int* __restrict__ bstart, const int* __restrict__ gcur,
    const uint2* __restrict__ ebuf, const float* __restrict__ W_rel,
    const float* __restrict__ loop_w, const float* __restrict__ evolve_w,
    float* __restrict__ out, int N) {
  __shared__ float sacc[NB * D];   // 16 KB
  __shared__ int   sflag[NB];
  for (int i = threadIdx.x; i < NB * D; i += 256) sacc[i] = 0.0f;
  if (threadIdx.x < NB) sflag[threadIdx.x] = 0;
  __syncthreads();

  const int lane = threadIdx.x & 63;
  const int wv   = __builtin_amdgcn_readfirstlane(threadIdx.x >> 6);
  const int b    = blockIdx.x;
  const int n0   = b << SHIFT;
  const int beg  = __builtin_amdgcn_readfirstlane(bstart[b]);
  const int end  = __builtin_amdgcn_readfirstlane(gcur[b]);   // == bucket end
  const int cnt  = end - beg;
  const int per  = (cnt + 3) >> 2;       // contiguous slice per wave
  int p       = beg + wv * per;
  const int pe = min(p + per, end);

  for (; p + 8 <= pe; p += 8) {          // 8 gathers in flight
    uint2 ee[8];
    #pragma unroll
    for (int q = 0; q < 8; ++q) ee[q] = ebuf[p + q];
    float ff[8];
    #pragma unroll
    for (int q = 0; q < 8; ++q)
      ff[q] = feat[(size_t)(ee[q].x & 0x03FFFFFFu) * D + lane];
    #pragma unroll
    for (int q = 0; q < 8; ++q) {
      const int dl = ee[q].x >> 26;
      atomicAdd(&sacc[dl * D + lane], __uint_as_float(ee[q].y) * ff[q]);
      if (lane == 0) sflag[dl] = 1;
    }
  }
  for (; p < pe; ++p) {
    const uint2 en = ebuf[p];
    const int dl = en.x >> 26;
    atomicAdd(&sacc[dl * D + lane],
              __uint_as_float(en.y) *
                  feat[(size_t)(en.x & 0x03FFFFFFu) * D + lane]);
    if (lane == 0) sflag[dl] = 1;
  }
  __syncthreads();

  for (int j = wv * (NB / 4); j < (wv + 1) * (NB / 4); ++j) {
    const int n = n0 + j;
    if (n >= N) break;
    const float f  = feat[(size_t)n * D + lane];
    const float nr = norm[n];
    float nf, lm = 0.0f;
    if (sflag[j]) {
      const float pa = sacc[j * D + lane];
      float a1 = 0.0f;
      #pragma unroll 8
      for (int k = 0; k < D; ++k) {
        const float fb = __shfl(f, k, 64);
        const float pb = __shfl(pa, k, 64);
        a1 += pb * W_rel[k * D + lane];
        lm += fb * loop_w[k * D + lane];
      }
      nf = a1 * nr;
    } else {
      #pragma unroll 8
      for (int k = 0; k < D; ++k) {
        const float fb = __shfl(f, k, 64);
        lm += fb * evolve_w[k * D + lane];
      }
      nf = f * nr;   // zero in-degree keeps old feat
    }
    out[(size_t)n * D + lane] = tanhf(nf + lm);
  }
}

extern "C" void kernel_launch(void* const* d_in, const int* in_sizes, int n_in,
                              void* d_out, int out_size, void* d_ws, size_t ws_size,
                              hipStream_t stream) {
  const float* feat     = (const float*)d_in[0];
  const float* norm     = (const float*)d_in[1];
  const int*   esrc     = (const int*)d_in[2];
  const int*   edst     = (const int*)d_in[3];
  // d_in[4] = etype: no-op permutation per the reference
  const float* W_rel    = (const float*)d_in[5];
  const float* lin_w    = (const float*)d_in[6];
  const float* lin_b    = (const float*)d_in[7];
  const float* loop_w   = (const float*)d_in[8];
  const float* evolve_w = (const float*)d_in[9];
  float* out = (float*)d_out;

  const int N = in_sizes[1];   // norm is [N]   (N <= 65536, src < 2^26)
  const int E = in_sizes[2];   // edge_src is [E]
  const int C = (N + NB - 1) >> SHIFT;   // 782 for N=50000

  // workspace: s1[N] | s2[N] | bstart[CMAX] | gcur[CMAX] | ghist[CMAX] | ebuf[E]
  float* s1     = (float*)d_ws;
  float* s2     = s1 + N;
  int*   bstart = (int*)(s2 + N);
  int*   gcur   = bstart + CMAX;
  int*   ghist  = gcur + CMAX;
  uint2* ebuf   = (uint2*)(ghist + CMAX);

  const int eblocks = (E + CHUNK - 1) / CHUNK;   // 196 for E=1.6M

  precompute_att<<<512, 256, 0, stream>>>(feat, lin_w, lin_b, s1, s2, ghist, C, N);
  coarse_hist<<<eblocks, 256, 0, stream>>>(edst, ghist, E, C);
  scan_coarse<<<1, 1024, 0, stream>>>(ghist, bstart, gcur, C);
  coarse_scatter<<<eblocks, 256, 0, stream>>>(esrc, edst, s1, s2, gcur, ebuf, E, C);
  bucket_reduce<<<C, 256, 0, stream>>>(feat, norm, bstart, gcur, ebuf,
                                       W_rel, loop_w, evolve_w, out, N);
}

// Round 7
// 285.829 us; speedup vs baseline: 3.2157x; 3.2157x over previous
//
#include <hip/hip_runtime.h>
#include <hip/hip_bf16.h>
#include <math.h>

// LGCN layer, coarse-bucket counting sort + fused in-LDS sort/reduce:
//   agg = segsum(atten*src) @ W_rel          (W_rel commutes out of the sum)
//   att_logit = s1[src] + s2[dst]            (lin_w splits into two per-node dots)
// R6 post-mortem: per-edge f32 LDS atomicAdd serialized bucket_reduce (789us,
//     VALUBusy 3.9% -> RMW/CAS chain per edge). R7: reducer now loads the
//     bucket's edges into LDS, counting-sorts them by dst-local with INT LDS
//     atomics (HW ds_add) + wave shfl-scan + rank pass, then each wave walks
//     contiguous per-node runs accumulating in REGISTERS (unroll-8 MLP).
//     Coarse scatter kept (it fixed the 8x write amplification of R5).

#define D 64
#define SHIFT 6
#define NB (1 << SHIFT)          // dst nodes per coarse bucket
#define CMAX 1024                // max buckets (requires N <= 65536)
#define CHUNK 8192               // edges per block in hist/scatter
#define CAP 3072                 // LDS edge capacity per sort chunk (mean 2048, sd 45)

// ---------------- kernel 1: per-node attention scalars + zero ghist ---------
__global__ __launch_bounds__(256) void precompute_att(
    const float* __restrict__ feat, const float* __restrict__ lin_w,
    const float* __restrict__ lin_b, float* __restrict__ s1,
    float* __restrict__ s2, int* __restrict__ ghist, int C, int N) {
  const int gt = blockIdx.x * 256 + threadIdx.x;
  for (int i = gt; i < C; i += gridDim.x * 256) ghist[i] = 0;

  const int lane = threadIdx.x & 63;
  const int wid  = (blockIdx.x * blockDim.x + threadIdx.x) >> 6;
  const int nw   = (gridDim.x * blockDim.x) >> 6;
  const float w1 = lin_w[lane];
  const float w2 = lin_w[64 + lane];
  const float b  = lin_b[0];
  for (int i = wid; i < N; i += nw) {
    const float f = feat[(size_t)i * D + lane];
    float v1 = f * w1;
    float v2 = f * w2;
    #pragma unroll
    for (int off = 32; off > 0; off >>= 1) {
      v1 += __shfl_down(v1, off, 64);
      v2 += __shfl_down(v2, off, 64);
    }
    if (lane == 0) {
      s1[i] = v1 + b;   // fold bias into s1
      s2[i] = v2;
    }
  }
}

// ---------------- kernel 2: coarse histogram (LDS-staged) ----------------
__global__ __launch_bounds__(256) void coarse_hist(
    const int* __restrict__ edst, int* __restrict__ ghist, int E, int C) {
  __shared__ int h[CMAX];
  for (int i = threadIdx.x; i < C; i += 256) h[i] = 0;
  __syncthreads();
  const int E4 = E >> 2;
  const int4* edst4 = (const int4*)edst;
  const int b4 = blockIdx.x * (CHUNK >> 2);
  #pragma unroll
  for (int k = 0; k < 8; ++k) {
    const int i4 = b4 + threadIdx.x + 256 * k;
    if (i4 < E4) {
      const int4 d = edst4[i4];
      atomicAdd(&h[d.x >> SHIFT], 1);
      atomicAdd(&h[d.y >> SHIFT], 1);
      atomicAdd(&h[d.z >> SHIFT], 1);
      atomicAdd(&h[d.w >> SHIFT], 1);
    }
  }
  if (blockIdx.x == 0 && threadIdx.x == 0) {      // E%4 tail
    for (int e = E4 << 2; e < E; ++e) atomicAdd(&h[edst[e] >> SHIFT], 1);
  }
  __syncthreads();
  for (int i = threadIdx.x; i < C; i += 256) {
    const int v = h[i];
    if (v) atomicAdd(&ghist[i], v);
  }
}

// ---------------- kernel 3: exclusive scan of C<=1024 bucket counts --------
__global__ __launch_bounds__(1024) void scan_coarse(
    const int* __restrict__ ghist, int* __restrict__ bstart,
    int* __restrict__ gcur, int C) {
  __shared__ int tot[1024];
  const int t = threadIdx.x;
  const int v = (t < C) ? ghist[t] : 0;
  tot[t] = v;
  __syncthreads();
  for (int off = 1; off < 1024; off <<= 1) {
    int u = tot[t] + ((t >= off) ? tot[t - off] : 0);
    __syncthreads();
    tot[t] = u;
    __syncthreads();
  }
  if (t < C) {
    bstart[t] = tot[t] - v;
    gcur[t]   = tot[t] - v;
  }
}

// ---------------- kernel 4: coarse scatter, LDS-staged runs ----------------
// Each block reserves one contiguous run per bucket (returning global atomic
// on gcur) and writes its chunk's edges grouped -> dense runs, no 8x
// line-writeback amplification. Entry: x = src | (dstlocal<<26), y = att f32.
__global__ __launch_bounds__(256) void coarse_scatter(
    const int* __restrict__ esrc, const int* __restrict__ edst,
    const float* __restrict__ s1, const float* __restrict__ s2,
    int* __restrict__ gcur, uint2* __restrict__ ebuf, int E, int C) {
  __shared__ int h[CMAX];
  __shared__ int cur[CMAX];
  __shared__ int bl[CMAX];
  for (int i = threadIdx.x; i < C; i += 256) h[i] = 0;
  __syncthreads();
  const int E4 = E >> 2;
  const int4* edst4 = (const int4*)edst;
  const int4* esrc4 = (const int4*)esrc;
  const int b4 = blockIdx.x * (CHUNK >> 2);
  const bool tail0 = (blockIdx.x == 0) && (threadIdx.x == 0);

  #pragma unroll
  for (int k = 0; k < 8; ++k) {
    const int i4 = b4 + threadIdx.x + 256 * k;
    if (i4 < E4) {
      const int4 d = edst4[i4];
      atomicAdd(&h[d.x >> SHIFT], 1);
      atomicAdd(&h[d.y >> SHIFT], 1);
      atomicAdd(&h[d.z >> SHIFT], 1);
      atomicAdd(&h[d.w >> SHIFT], 1);
    }
  }
  if (tail0) for (int e = E4 << 2; e < E; ++e) atomicAdd(&h[edst[e] >> SHIFT], 1);
  __syncthreads();
  for (int i = threadIdx.x; i < C; i += 256) {
    const int v = h[i];
    bl[i] = v ? atomicAdd(&gcur[i], v) : 0;
    cur[i] = 0;
  }
  __syncthreads();

  #pragma unroll
  for (int k = 0; k < 8; ++k) {
    const int i4 = b4 + threadIdx.x + 256 * k;
    if (i4 < E4) {
      const int4 s = esrc4[i4];
      const int4 d = edst4[i4];
      const int ss[4] = {s.x, s.y, s.z, s.w};
      const int dd[4] = {d.x, d.y, d.z, d.w};
      float a1[4], a2[4];
      #pragma unroll
      for (int j = 0; j < 4; ++j) a1[j] = s1[ss[j]];   // independent gathers
      #pragma unroll
      for (int j = 0; j < 4; ++j) a2[j] = s2[dd[j]];
      #pragma unroll
      for (int j = 0; j < 4; ++j) {
        const float a = 1.0f / (1.0f + __expf(-fmaxf(a1[j] + a2[j], 0.0f)));
        const int bk = dd[j] >> SHIFT;
        const int r  = atomicAdd(&cur[bk], 1);
        ebuf[bl[bk] + r] =
            make_uint2((unsigned)ss[j] | ((unsigned)(dd[j] & (NB - 1)) << 26),
                       __float_as_uint(a));
      }
    }
  }
  if (tail0) {
    for (int e = E4 << 2; e < E; ++e) {
      const int sj = esrc[e], dj = edst[e];
      const float a = 1.0f / (1.0f + __expf(-fmaxf(s1[sj] + s2[dj], 0.0f)));
      const int bk = dj >> SHIFT;
      const int r  = atomicAdd(&cur[bk], 1);
      ebuf[bl[bk] + r] =
          make_uint2((unsigned)sj | ((unsigned)(dj & (NB - 1)) << 26),
                     __float_as_uint(a));
    }
  }
}

// ---------------- kernel 5: in-LDS counting sort + register reduce ----------
// One block (512 thr, 8 waves) per coarse bucket. Sort: int LDS hist (HW
// ds_add) -> wave-0 shfl scan -> rank pass builds perm. Reduce: wave wv walks
// nodes wv*8..wv*8+7; per node the run [roff[j], roff[j+1]) is contiguous in
// perm; accumulate att*feat[src] in registers with unroll-8 gathers in flight.
__global__ __launch_bounds__(512, 6) void bucket_reduce(
    const float* __restrict__ feat, const float* __restrict__ norm,
    const int* __restrict__ bstart, const int* __restrict__ gcur,
    const uint2* __restrict__ ebuf, const float* __restrict__ W_rel,
    const float* __restrict__ loop_w, const float* __restrict__ evolve_w,
    float* __restrict__ out, int N) {
  __shared__ uint2  sent[CAP];       // 24 KB
  __shared__ unsigned short perm[CAP];  // 6 KB
  __shared__ int hist[NB];
  __shared__ int roff[NB + 1];

  const int tid  = threadIdx.x;
  const int lane = tid & 63;
  const int wv   = __builtin_amdgcn_readfirstlane(tid >> 6);   // 0..7
  const int b    = blockIdx.x;
  const int n0   = b << SHIFT;
  const int beg  = __builtin_amdgcn_readfirstlane(bstart[b]);
  const int end  = __builtin_amdgcn_readfirstlane(gcur[b]);    // bucket end

  float acc[8];
  int   deg[8];
  #pragma unroll
  for (int j = 0; j < 8; ++j) { acc[j] = 0.0f; deg[j] = 0; }

  for (int cb = beg; cb < end; cb += CAP) {       // single chunk in practice
    const int ccnt = min(CAP, end - cb);
    __syncthreads();                               // protect prev sent/perm
    if (tid < NB) hist[tid] = 0;
    __syncthreads();
    // load edges into LDS + int histogram (HW ds_add, fast)
    for (int i = tid; i < ccnt; i += 512) {
      const uint2 e = ebuf[cb + i];
      sent[i] = e;
      atomicAdd(&hist[e.x >> 26], 1);
    }
    __syncthreads();
    // wave 0: shfl inclusive scan of 64 counts -> roff; reset hist for rank
    if (tid < 64) {
      const int v = hist[tid];
      int incl = v;
      #pragma unroll
      for (int off = 1; off < 64; off <<= 1) {
        const int o = __shfl_up(incl, off, 64);
        if (tid >= off) incl += o;
      }
      roff[tid + 1] = incl;
      if (tid == 0) roff[0] = 0;
      hist[tid] = 0;
    }
    __syncthreads();
    // rank pass: perm[roff[dl] + rank] = LDS index
    for (int i = tid; i < ccnt; i += 512) {
      const int dl = sent[i].x >> 26;
      const int r  = atomicAdd(&hist[dl], 1);
      perm[roff[dl] + r] = (unsigned short)i;
    }
    __syncthreads();
    // register accumulate: wave wv -> nodes wv*8 .. wv*8+7
    #pragma unroll
    for (int jj = 0; jj < 8; ++jj) {
      const int j  = wv * 8 + jj;
      const int pb = __builtin_amdgcn_readfirstlane(roff[j]);
      const int pe = __builtin_amdgcn_readfirstlane(roff[j + 1]);
      deg[jj] += pe - pb;
      int p = pb;
      for (; p + 8 <= pe; p += 8) {
        int idx[8];
        #pragma unroll
        for (int q = 0; q < 8; ++q) idx[q] = perm[p + q];
        uint2 ent[8];
        #pragma unroll
        for (int q = 0; q < 8; ++q) ent[q] = sent[idx[q]];
        float ff[8];
        #pragma unroll
        for (int q = 0; q < 8; ++q)
          ff[q] = feat[(size_t)(ent[q].x & 0x03FFFFFFu) * D + lane];
        #pragma unroll
        for (int q = 0; q < 8; ++q)
          acc[jj] += __uint_as_float(ent[q].y) * ff[q];
      }
      for (; p < pe; ++p) {
        const uint2 en = sent[perm[p]];
        acc[jj] += __uint_as_float(en.y) *
                   feat[(size_t)(en.x & 0x03FFFFFFu) * D + lane];
      }
    }
  }

  // epilogue: matvecs + tanh for this wave's 8 nodes
  #pragma unroll
  for (int jj = 0; jj < 8; ++jj) {
    const int n = n0 + wv * 8 + jj;
    if (n >= N) break;
    const float f  = feat[(size_t)n * D + lane];
    const float nr = norm[n];
    float nf, lm = 0.0f;
    if (deg[jj] > 0) {
      const float pa = acc[jj];
      float a1 = 0.0f;
      #pragma unroll 8
      for (int k = 0; k < D; ++k) {
        const float fb = __shfl(f, k, 64);
        const float pb = __shfl(pa, k, 64);
        a1 += pb * W_rel[k * D + lane];
        lm += fb * loop_w[k * D + lane];
      }
      nf = a1 * nr;
    } else {
      #pragma unroll 8
      for (int k = 0; k < D; ++k) {
        const float fb = __shfl(f, k, 64);
        lm += fb * evolve_w[k * D + lane];
      }
      nf = f * nr;   // zero in-degree keeps old feat
    }
    out[(size_t)n * D + lane] = tanhf(nf + lm);
  }
}

extern "C" void kernel_launch(void* const* d_in, const int* in_sizes, int n_in,
                              void* d_out, int out_size, void* d_ws, size_t ws_size,
                              hipStream_t stream) {
  const float* feat     = (const float*)d_in[0];
  const float* norm     = (const float*)d_in[1];
  const int*   esrc     = (const int*)d_in[2];
  const int*   edst     = (const int*)d_in[3];
  // d_in[4] = etype: no-op permutation per the reference
  const float* W_rel    = (const float*)d_in[5];
  const float* lin_w    = (const float*)d_in[6];
  const float* lin_b    = (const float*)d_in[7];
  const float* loop_w   = (const float*)d_in[8];
  const float* evolve_w = (const float*)d_in[9];
  float* out = (float*)d_out;

  const int N = in_sizes[1];   // norm is [N]   (N <= 65536, src < 2^26)
  const int E = in_sizes[2];   // edge_src is [E]
  const int C = (N + NB - 1) >> SHIFT;   // 782 for N=50000

  // workspace: s1[N] | s2[N] | bstart[CMAX] | gcur[CMAX] | ghist[CMAX] | ebuf[E]
  float* s1     = (float*)d_ws;
  float* s2     = s1 + N;
  int*   bstart = (int*)(s2 + N);
  int*   gcur   = bstart + CMAX;
  int*   ghist  = gcur + CMAX;
  uint2* ebuf   = (uint2*)(ghist + CMAX);

  const int eblocks = (E + CHUNK - 1) / CHUNK;   // 196 for E=1.6M

  precompute_att<<<512, 256, 0, stream>>>(feat, lin_w, lin_b, s1, s2, ghist, C, N);
  coarse_hist<<<eblocks, 256, 0, stream>>>(edst, ghist, E, C);
  scan_coarse<<<1, 1024, 0, stream>>>(ghist, bstart, gcur, C);
  coarse_scatter<<<eblocks, 256, 0, stream>>>(esrc, edst, s1, s2, gcur, ebuf, E, C);
  bucket_reduce<<<C, 512, 0, stream>>>(feat, norm, bstart, gcur, ebuf,
                                       W_rel, loop_w, evolve_w, out, N);
}

// Round 8
// 284.972 us; speedup vs baseline: 3.2254x; 1.0030x over previous
//
#include <hip/hip_runtime.h>
#include <hip/hip_bf16.h>
#include <math.h>

// LGCN layer, coarse-bucket counting sort + fused in-LDS sort/reduce:
//   agg = segsum(atten*src) @ W_rel          (W_rel commutes out of the sum)
//   att_logit = s1[src] + s2[dst]            (lin_w splits into two per-node dots)
// R7 post-mortem: bucket_reduce was LDS-pipe bound at 7 ds-ops/edge (~110us
//     floor; 471K bank-conflict cycles from b16 perm traffic). R8: 4 ds-ops
//     per edge — ebuf read twice from global (coalesced, L2-resident);
//     pass 1 = hist ds_add; pass 2 = rank ds_add on roff (consumed offsets,
//     R4 trick) + direct ds_write_b64 into SORTED slot; accumulate does one
//     sequential ds_read_b64. No sent staging, no perm. CHUNK 8192->4096.

#define D 64
#define SHIFT 6
#define NB (1 << SHIFT)          // dst nodes per coarse bucket
#define CMAX 1024                // max buckets (requires N <= 65536)
#define CHUNK 4096               // edges per block in hist/scatter
#define CAP 3072                 // LDS edge capacity per sort chunk (mean 2048)

// ---------------- kernel 1: per-node attention scalars + zero ghist ---------
__global__ __launch_bounds__(256) void precompute_att(
    const float* __restrict__ feat, const float* __restrict__ lin_w,
    const float* __restrict__ lin_b, float* __restrict__ s1,
    float* __restrict__ s2, int* __restrict__ ghist, int C, int N) {
  const int gt = blockIdx.x * 256 + threadIdx.x;
  for (int i = gt; i < C; i += gridDim.x * 256) ghist[i] = 0;

  const int lane = threadIdx.x & 63;
  const int wid  = (blockIdx.x * blockDim.x + threadIdx.x) >> 6;
  const int nw   = (gridDim.x * blockDim.x) >> 6;
  const float w1 = lin_w[lane];
  const float w2 = lin_w[64 + lane];
  const float b  = lin_b[0];
  for (int i = wid; i < N; i += nw) {
    const float f = feat[(size_t)i * D + lane];
    float v1 = f * w1;
    float v2 = f * w2;
    #pragma unroll
    for (int off = 32; off > 0; off >>= 1) {
      v1 += __shfl_down(v1, off, 64);
      v2 += __shfl_down(v2, off, 64);
    }
    if (lane == 0) {
      s1[i] = v1 + b;   // fold bias into s1
      s2[i] = v2;
    }
  }
}

// ---------------- kernel 2: coarse histogram (LDS-staged) ----------------
__global__ __launch_bounds__(256) void coarse_hist(
    const int* __restrict__ edst, int* __restrict__ ghist, int E, int C) {
  __shared__ int h[CMAX];
  for (int i = threadIdx.x; i < C; i += 256) h[i] = 0;
  __syncthreads();
  const int E4 = E >> 2;
  const int4* edst4 = (const int4*)edst;
  const int b4 = blockIdx.x * (CHUNK >> 2);
  #pragma unroll
  for (int k = 0; k < CHUNK / 1024; ++k) {
    const int i4 = b4 + threadIdx.x + 256 * k;
    if (i4 < E4) {
      const int4 d = edst4[i4];
      atomicAdd(&h[d.x >> SHIFT], 1);
      atomicAdd(&h[d.y >> SHIFT], 1);
      atomicAdd(&h[d.z >> SHIFT], 1);
      atomicAdd(&h[d.w >> SHIFT], 1);
    }
  }
  if (blockIdx.x == 0 && threadIdx.x == 0) {      // E%4 tail
    for (int e = E4 << 2; e < E; ++e) atomicAdd(&h[edst[e] >> SHIFT], 1);
  }
  __syncthreads();
  for (int i = threadIdx.x; i < C; i += 256) {
    const int v = h[i];
    if (v) atomicAdd(&ghist[i], v);
  }
}

// ---------------- kernel 3: exclusive scan of C<=1024 bucket counts --------
__global__ __launch_bounds__(1024) void scan_coarse(
    const int* __restrict__ ghist, int* __restrict__ bstart,
    int* __restrict__ gcur, int C) {
  __shared__ int tot[1024];
  const int t = threadIdx.x;
  const int v = (t < C) ? ghist[t] : 0;
  tot[t] = v;
  __syncthreads();
  for (int off = 1; off < 1024; off <<= 1) {
    int u = tot[t] + ((t >= off) ? tot[t - off] : 0);
    __syncthreads();
    tot[t] = u;
    __syncthreads();
  }
  if (t < C) {
    bstart[t] = tot[t] - v;
    gcur[t]   = tot[t] - v;
  }
}

// ---------------- kernel 4: coarse scatter, LDS-staged runs ----------------
// Each block reserves one contiguous run per bucket (returning global atomic
// on gcur) and writes its chunk's edges grouped -> dense runs, no 8x
// line-writeback amplification. Entry: x = src | (dstlocal<<26), y = att f32.
__global__ __launch_bounds__(256) void coarse_scatter(
    const int* __restrict__ esrc, const int* __restrict__ edst,
    const float* __restrict__ s1, const float* __restrict__ s2,
    int* __restrict__ gcur, uint2* __restrict__ ebuf, int E, int C) {
  __shared__ int h[CMAX];
  __shared__ int cur[CMAX];
  __shared__ int bl[CMAX];
  for (int i = threadIdx.x; i < C; i += 256) h[i] = 0;
  __syncthreads();
  const int E4 = E >> 2;
  const int4* edst4 = (const int4*)edst;
  const int4* esrc4 = (const int4*)esrc;
  const int b4 = blockIdx.x * (CHUNK >> 2);
  const bool tail0 = (blockIdx.x == 0) && (threadIdx.x == 0);

  #pragma unroll
  for (int k = 0; k < CHUNK / 1024; ++k) {
    const int i4 = b4 + threadIdx.x + 256 * k;
    if (i4 < E4) {
      const int4 d = edst4[i4];
      atomicAdd(&h[d.x >> SHIFT], 1);
      atomicAdd(&h[d.y >> SHIFT], 1);
      atomicAdd(&h[d.z >> SHIFT], 1);
      atomicAdd(&h[d.w >> SHIFT], 1);
    }
  }
  if (tail0) for (int e = E4 << 2; e < E; ++e) atomicAdd(&h[edst[e] >> SHIFT], 1);
  __syncthreads();
  for (int i = threadIdx.x; i < C; i += 256) {
    const int v = h[i];
    bl[i] = v ? atomicAdd(&gcur[i], v) : 0;
    cur[i] = 0;
  }
  __syncthreads();

  #pragma unroll
  for (int k = 0; k < CHUNK / 1024; ++k) {
    const int i4 = b4 + threadIdx.x + 256 * k;
    if (i4 < E4) {
      const int4 s = esrc4[i4];
      const int4 d = edst4[i4];
      const int ss[4] = {s.x, s.y, s.z, s.w};
      const int dd[4] = {d.x, d.y, d.z, d.w};
      float a1[4], a2[4];
      #pragma unroll
      for (int j = 0; j < 4; ++j) a1[j] = s1[ss[j]];   // independent gathers
      #pragma unroll
      for (int j = 0; j < 4; ++j) a2[j] = s2[dd[j]];
      #pragma unroll
      for (int j = 0; j < 4; ++j) {
        const float a = 1.0f / (1.0f + __expf(-fmaxf(a1[j] + a2[j], 0.0f)));
        const int bk = dd[j] >> SHIFT;
        const int r  = atomicAdd(&cur[bk], 1);
        ebuf[bl[bk] + r] =
            make_uint2((unsigned)ss[j] | ((unsigned)(dd[j] & (NB - 1)) << 26),
                       __float_as_uint(a));
      }
    }
  }
  if (tail0) {
    for (int e = E4 << 2; e < E; ++e) {
      const int sj = esrc[e], dj = edst[e];
      const float a = 1.0f / (1.0f + __expf(-fmaxf(s1[sj] + s2[dj], 0.0f)));
      const int bk = dj >> SHIFT;
      const int r  = atomicAdd(&cur[bk], 1);
      ebuf[bl[bk] + r] =
          make_uint2((unsigned)sj | ((unsigned)(dj & (NB - 1)) << 26),
                     __float_as_uint(a));
    }
  }
}

// ---------------- kernel 5: in-LDS counting sort + register reduce ----------
// One block (512 thr, 8 waves) per coarse bucket. 4 LDS ops per edge:
//   pass 1: ds_add hist (dl from ebuf.x, global read)
//   scan  : wave-0 shfl exclusive scan -> roff[64] (starts)
//   pass 2: ds_add rank on roff (consumed -> becomes run ENDS) +
//           ds_write_b64 of the entry directly into its sorted slot
//   accum : sequential ds_read_b64; run j = [j==0?0:roff[j-1], roff[j])
__global__ __launch_bounds__(512, 6) void bucket_reduce(
    const float* __restrict__ feat, const float* __restrict__ norm,
    const int* __restrict__ bstart, const int* __restrict__ gcur,
    const uint2* __restrict__ ebuf, const float* __restrict__ W_rel,
    const float* __restrict__ loop_w, const float* __restrict__ evolve_w,
    float* __restrict__ out, int N) {
  __shared__ uint2 sdata[CAP];    // sorted entries, 24 KB
  __shared__ int   hist[NB];
  __shared__ int   roff[NB];      // exclusive starts -> consumed into ends

  const int tid  = threadIdx.x;
  const int lane = tid & 63;
  const int wv   = __builtin_amdgcn_readfirstlane(tid >> 6);   // 0..7
  const int b    = blockIdx.x;
  const int n0   = b << SHIFT;
  const int beg  = __builtin_amdgcn_readfirstlane(bstart[b]);
  const int end  = __builtin_amdgcn_readfirstlane(gcur[b]);    // bucket end

  float acc[8];
  int   deg[8];
  #pragma unroll
  for (int j = 0; j < 8; ++j) { acc[j] = 0.0f; deg[j] = 0; }

  for (int cb = beg; cb < end; cb += CAP) {       // single chunk in practice
    const int ccnt = min(CAP, end - cb);
    __syncthreads();                               // protect prev sdata/roff
    if (tid < NB) hist[tid] = 0;
    __syncthreads();
    // pass 1: histogram (dl only; coalesced global read)
    for (int i = tid; i < ccnt; i += 512) {
      const unsigned x = ebuf[cb + i].x;
      atomicAdd(&hist[x >> 26], 1);
    }
    __syncthreads();
    // wave 0: shfl exclusive scan of 64 counts -> roff (starts)
    if (tid < 64) {
      const int v = hist[tid];
      int incl = v;
      #pragma unroll
      for (int off = 1; off < 64; off <<= 1) {
        const int o = __shfl_up(incl, off, 64);
        if (tid >= off) incl += o;
      }
      roff[tid] = incl - v;
    }
    __syncthreads();
    // pass 2: rank atomic on roff + direct sorted placement (re-read global)
    for (int i = tid; i < ccnt; i += 512) {
      const uint2 e = ebuf[cb + i];
      const int pos = atomicAdd(&roff[e.x >> 26], 1);
      sdata[pos] = e;
    }
    __syncthreads();
    // register accumulate: wave wv -> nodes wv*8 .. wv*8+7
    #pragma unroll
    for (int jj = 0; jj < 8; ++jj) {
      const int j  = wv * 8 + jj;
      const int pb = __builtin_amdgcn_readfirstlane(j == 0 ? 0 : roff[j - 1]);
      const int pe = __builtin_amdgcn_readfirstlane(roff[j]);
      deg[jj] += pe - pb;
      int p = pb;
      for (; p + 8 <= pe; p += 8) {
        uint2 ent[8];
        #pragma unroll
        for (int q = 0; q < 8; ++q) ent[q] = sdata[p + q];
        float ff[8];
        #pragma unroll
        for (int q = 0; q < 8; ++q)
          ff[q] = feat[(size_t)(ent[q].x & 0x03FFFFFFu) * D + lane];
        #pragma unroll
        for (int q = 0; q < 8; ++q)
          acc[jj] += __uint_as_float(ent[q].y) * ff[q];
      }
      for (; p < pe; ++p) {
        const uint2 en = sdata[p];
        acc[jj] += __uint_as_float(en.y) *
                   feat[(size_t)(en.x & 0x03FFFFFFu) * D + lane];
      }
    }
  }

  // epilogue: matvecs + tanh for this wave's 8 nodes
  #pragma unroll
  for (int jj = 0; jj < 8; ++jj) {
    const int n = n0 + wv * 8 + jj;
    if (n >= N) break;
    const float f  = feat[(size_t)n * D + lane];
    const float nr = norm[n];
    float nf, lm = 0.0f;
    if (deg[jj] > 0) {
      const float pa = acc[jj];
      float a1 = 0.0f;
      #pragma unroll 8
      for (int k = 0; k < D; ++k) {
        const float fb = __shfl(f, k, 64);
        const float pb = __shfl(pa, k, 64);
        a1 += pb * W_rel[k * D + lane];
        lm += fb * loop_w[k * D + lane];
      }
      nf = a1 * nr;
    } else {
      #pragma unroll 8
      for (int k = 0; k < D; ++k) {
        const float fb = __shfl(f, k, 64);
        lm += fb * evolve_w[k * D + lane];
      }
      nf = f * nr;   // zero in-degree keeps old feat
    }
    out[(size_t)n * D + lane] = tanhf(nf + lm);
  }
}

extern "C" void kernel_launch(void* const* d_in, const int* in_sizes, int n_in,
                              void* d_out, int out_size, void* d_ws, size_t ws_size,
                              hipStream_t stream) {
  const float* feat     = (const float*)d_in[0];
  const float* norm     = (const float*)d_in[1];
  const int*   esrc     = (const int*)d_in[2];
  const int*   edst     = (const int*)d_in[3];
  // d_in[4] = etype: no-op permutation per the reference
  const float* W_rel    = (const float*)d_in[5];
  const float* lin_w    = (const float*)d_in[6];
  const float* lin_b    = (const float*)d_in[7];
  const float* loop_w   = (const float*)d_in[8];
  const float* evolve_w = (const float*)d_in[9];
  float* out = (float*)d_out;

  const int N = in_sizes[1];   // norm is [N]   (N <= 65536, src < 2^26)
  const int E = in_sizes[2];   // edge_src is [E]
  const int C = (N + NB - 1) >> SHIFT;   // 782 for N=50000

  // workspace: s1[N] | s2[N] | bstart[CMAX] | gcur[CMAX] | ghist[CMAX] | ebuf[E]
  float* s1     = (float*)d_ws;
  float* s2     = s1 + N;
  int*   bstart = (int*)(s2 + N);
  int*   gcur   = bstart + CMAX;
  int*   ghist  = gcur + CMAX;
  uint2* ebuf   = (uint2*)(ghist + CMAX);

  const int eblocks = (E + CHUNK - 1) / CHUNK;   // 391 for E=1.6M

  precompute_att<<<512, 256, 0, stream>>>(feat, lin_w, lin_b, s1, s2, ghist, C, N);
  coarse_hist<<<eblocks, 256, 0, stream>>>(edst, ghist, E, C);
  scan_coarse<<<1, 1024, 0, stream>>>(ghist, bstart, gcur, C);
  coarse_scatter<<<eblocks, 256, 0, stream>>>(esrc, edst, s1, s2, gcur, ebuf, E, C);
  bucket_reduce<<<C, 512, 0, stream>>>(feat, norm, bstart, gcur, ebuf,
                                       W_rel, loop_w, evolve_w, out, N);
}

// Round 9
// 282.156 us; speedup vs baseline: 3.2576x; 1.0100x over previous
//
#include <hip/hip_runtime.h>
#include <hip/hip_bf16.h>
#include <math.h>

// LGCN layer, coarse-bucket counting sort + fused in-LDS sort/reduce:
//   agg = segsum(atten*src) @ W_rel          (W_rel commutes out of the sum)
//   att_logit = s1[src] + s2[dst]            (lin_w splits into two per-node dots)
// R8 post-mortem: LDS-op count was NOT the limit; bucket_reduce is gather-MLP
//     bound (R4 evidence: 16-deep unroll sustained 1.75 TB/s vs our 1.17 at
//     8-deep) and tail-bound (782 blocks / 4-per-CU cap -> 44% occupancy).
// R9: unroll 16; SHIFT 6->5 (NB=32, C=1563, 256-thr blocks, CAP 2048,
//     16 KB LDS) -> all blocks resident at once, no tail; coarse_hist fused
//     into precompute_att (LDS-staged) + memset for ghist.

#define D 64
#define SHIFT 5
#define NB (1 << SHIFT)          // dst nodes per coarse bucket (32)
#define CMAX 2048                // max buckets (requires N <= 65536)
#define CHUNK 4096               // edges per block in scatter
#define CAP 2048                 // LDS edge capacity per sort chunk (mean 1024)

// ------- kernel 1: per-node attention scalars + LDS-staged coarse hist ------
__global__ __launch_bounds__(256) void precompute_att(
    const float* __restrict__ feat, const float* __restrict__ lin_w,
    const float* __restrict__ lin_b, const int* __restrict__ edst,
    float* __restrict__ s1, float* __restrict__ s2,
    int* __restrict__ ghist, int C, int N, int E) {
  __shared__ int h[CMAX];
  for (int i = threadIdx.x; i < C; i += 256) h[i] = 0;
  __syncthreads();

  // edge histogram into LDS (int4, grid-stride)
  const int E4 = E >> 2;
  const int4* edst4 = (const int4*)edst;
  for (int i4 = blockIdx.x * 256 + threadIdx.x; i4 < E4;
       i4 += gridDim.x * 256) {
    const int4 d = edst4[i4];
    atomicAdd(&h[d.x >> SHIFT], 1);
    atomicAdd(&h[d.y >> SHIFT], 1);
    atomicAdd(&h[d.z >> SHIFT], 1);
    atomicAdd(&h[d.w >> SHIFT], 1);
  }
  if (blockIdx.x == 0 && threadIdx.x == 0) {      // E%4 tail
    for (int e = E4 << 2; e < E; ++e) atomicAdd(&h[edst[e] >> SHIFT], 1);
  }

  // per-node attention scalars (independent of hist)
  const int lane = threadIdx.x & 63;
  const int wid  = (blockIdx.x * blockDim.x + threadIdx.x) >> 6;
  const int nw   = (gridDim.x * blockDim.x) >> 6;
  const float w1 = lin_w[lane];
  const float w2 = lin_w[64 + lane];
  const float b  = lin_b[0];
  for (int i = wid; i < N; i += nw) {
    const float f = feat[(size_t)i * D + lane];
    float v1 = f * w1;
    float v2 = f * w2;
    #pragma unroll
    for (int off = 32; off > 0; off >>= 1) {
      v1 += __shfl_down(v1, off, 64);
      v2 += __shfl_down(v2, off, 64);
    }
    if (lane == 0) {
      s1[i] = v1 + b;   // fold bias into s1
      s2[i] = v2;
    }
  }

  __syncthreads();
  for (int i = threadIdx.x; i < C; i += 256) {
    const int v = h[i];
    if (v) atomicAdd(&ghist[i], v);   // ghist pre-zeroed by memsetAsync
  }
}

// ------- kernel 2: exclusive scan of C<=2048 bucket counts (2 items/thread) --
__global__ __launch_bounds__(1024) void scan_coarse(
    const int* __restrict__ ghist, int* __restrict__ bstart,
    int* __restrict__ gcur, int C) {
  __shared__ int tot[1024];
  const int t = threadIdx.x;
  const int i0 = 2 * t, i1 = 2 * t + 1;
  const int v0 = (i0 < C) ? ghist[i0] : 0;
  const int v1 = (i1 < C) ? ghist[i1] : 0;
  const int s = v0 + v1;
  tot[t] = s;
  __syncthreads();
  for (int off = 1; off < 1024; off <<= 1) {
    int u = tot[t] + ((t >= off) ? tot[t - off] : 0);
    __syncthreads();
    tot[t] = u;
    __syncthreads();
  }
  const int excl = tot[t] - s;
  if (i0 < C) { bstart[i0] = excl;      gcur[i0] = excl; }
  if (i1 < C) { bstart[i1] = excl + v0; gcur[i1] = excl + v0; }
}

// ---------------- kernel 3: coarse scatter, LDS-staged runs ----------------
// Each block reserves one contiguous run per bucket (returning global atomic
// on gcur) and writes its chunk's edges grouped -> dense runs, no 8x
// line-writeback amplification. Entry: x = src | (dstlocal<<26), y = att f32.
__global__ __launch_bounds__(256) void coarse_scatter(
    const int* __restrict__ esrc, const int* __restrict__ edst,
    const float* __restrict__ s1, const float* __restrict__ s2,
    int* __restrict__ gcur, uint2* __restrict__ ebuf, int E, int C) {
  __shared__ int h[CMAX];
  __shared__ int cur[CMAX];
  __shared__ int bl[CMAX];
  for (int i = threadIdx.x; i < C; i += 256) h[i] = 0;
  __syncthreads();
  const int E4 = E >> 2;
  const int4* edst4 = (const int4*)edst;
  const int4* esrc4 = (const int4*)esrc;
  const int b4 = blockIdx.x * (CHUNK >> 2);
  const bool tail0 = (blockIdx.x == 0) && (threadIdx.x == 0);

  #pragma unroll
  for (int k = 0; k < CHUNK / 1024; ++k) {
    const int i4 = b4 + threadIdx.x + 256 * k;
    if (i4 < E4) {
      const int4 d = edst4[i4];
      atomicAdd(&h[d.x >> SHIFT], 1);
      atomicAdd(&h[d.y >> SHIFT], 1);
      atomicAdd(&h[d.z >> SHIFT], 1);
      atomicAdd(&h[d.w >> SHIFT], 1);
    }
  }
  if (tail0) for (int e = E4 << 2; e < E; ++e) atomicAdd(&h[edst[e] >> SHIFT], 1);
  __syncthreads();
  for (int i = threadIdx.x; i < C; i += 256) {
    const int v = h[i];
    bl[i] = v ? atomicAdd(&gcur[i], v) : 0;
    cur[i] = 0;
  }
  __syncthreads();

  #pragma unroll
  for (int k = 0; k < CHUNK / 1024; ++k) {
    const int i4 = b4 + threadIdx.x + 256 * k;
    if (i4 < E4) {
      const int4 s = esrc4[i4];
      const int4 d = edst4[i4];
      const int ss[4] = {s.x, s.y, s.z, s.w};
      const int dd[4] = {d.x, d.y, d.z, d.w};
      float a1[4], a2[4];
      #pragma unroll
      for (int j = 0; j < 4; ++j) a1[j] = s1[ss[j]];   // independent gathers
      #pragma unroll
      for (int j = 0; j < 4; ++j) a2[j] = s2[dd[j]];
      #pragma unroll
      for (int j = 0; j < 4; ++j) {
        const float a = 1.0f / (1.0f + __expf(-fmaxf(a1[j] + a2[j], 0.0f)));
        const int bk = dd[j] >> SHIFT;
        const int r  = atomicAdd(&cur[bk], 1);
        ebuf[bl[bk] + r] =
            make_uint2((unsigned)ss[j] | ((unsigned)(dd[j] & (NB - 1)) << 26),
                       __float_as_uint(a));
      }
    }
  }
  if (tail0) {
    for (int e = E4 << 2; e < E; ++e) {
      const int sj = esrc[e], dj = edst[e];
      const float a = 1.0f / (1.0f + __expf(-fmaxf(s1[sj] + s2[dj], 0.0f)));
      const int bk = dj >> SHIFT;
      const int r  = atomicAdd(&cur[bk], 1);
      ebuf[bl[bk] + r] =
          make_uint2((unsigned)sj | ((unsigned)(dj & (NB - 1)) << 26),
                     __float_as_uint(a));
    }
  }
}

// ---------------- kernel 4: in-LDS counting sort + register reduce ----------
// One block (256 thr, 4 waves) per coarse bucket of NB=32 dst nodes.
// 4 LDS ops/edge: hist ds_add; wave-0 shfl scan -> roff starts; rank ds_add
// (consumed -> run ends) + direct sorted ds_write_b64; sequential ds_read_b64.
// Run walk: unroll 16 -> 16 gathers in flight (R4 evidence: sustains 1.75TB/s).
__global__ __launch_bounds__(256, 8) void bucket_reduce(
    const float* __restrict__ feat, const float* __restrict__ norm,
    const int* __restrict__ bstart, const int* __restrict__ gcur,
    const uint2* __restrict__ ebuf, const float* __restrict__ W_rel,
    const float* __restrict__ loop_w, const float* __restrict__ evolve_w,
    float* __restrict__ out, int N) {
  __shared__ uint2 sdata[CAP];    // sorted entries, 16 KB
  __shared__ int   hist[NB];
  __shared__ int   roff[NB];      // exclusive starts -> consumed into ends

  const int tid  = threadIdx.x;
  const int lane = tid & 63;
  const int wv   = __builtin_amdgcn_readfirstlane(tid >> 6);   // 0..3
  const int b    = blockIdx.x;
  const int n0   = b << SHIFT;
  const int beg  = __builtin_amdgcn_readfirstlane(bstart[b]);
  const int end  = __builtin_amdgcn_readfirstlane(gcur[b]);    // bucket end

  float acc[NB / 4];
  int   deg[NB / 4];
  #pragma unroll
  for (int j = 0; j < NB / 4; ++j) { acc[j] = 0.0f; deg[j] = 0; }

  for (int cb = beg; cb < end; cb += CAP) {       // single chunk in practice
    const int ccnt = min(CAP, end - cb);
    __syncthreads();                               // protect prev sdata/roff
    if (tid < NB) hist[tid] = 0;
    __syncthreads();
    // pass 1: histogram (dl only; coalesced 4B global read)
    for (int i = tid; i < ccnt; i += 256) {
      const unsigned x = ebuf[cb + i].x;
      atomicAdd(&hist[x >> 26], 1);
    }
    __syncthreads();
    // lanes 0..NB-1 of wave 0: shfl exclusive scan -> roff (starts)
    if (tid < NB) {
      const int v = hist[tid];
      int incl = v;
      #pragma unroll
      for (int off = 1; off < NB; off <<= 1) {
        const int o = __shfl_up(incl, off, 64);
        if (tid >= off) incl += o;
      }
      roff[tid] = incl - v;
    }
    __syncthreads();
    // pass 2: rank atomic on roff + direct sorted placement (re-read global)
    for (int i = tid; i < ccnt; i += 256) {
      const uint2 e = ebuf[cb + i];
      const int pos = atomicAdd(&roff[e.x >> 26], 1);
      sdata[pos] = e;
    }
    __syncthreads();
    // register accumulate: wave wv -> nodes wv*8 .. wv*8+7; unroll 16
    #pragma unroll
    for (int jj = 0; jj < NB / 4; ++jj) {
      const int j  = wv * (NB / 4) + jj;
      const int pb = __builtin_amdgcn_readfirstlane(j == 0 ? 0 : roff[j - 1]);
      const int pe = __builtin_amdgcn_readfirstlane(roff[j]);
      deg[jj] += pe - pb;
      int p = pb;
      for (; p + 16 <= pe; p += 16) {
        uint2 ent[16];
        #pragma unroll
        for (int q = 0; q < 16; ++q) ent[q] = sdata[p + q];
        float ff[16];
        #pragma unroll
        for (int q = 0; q < 16; ++q)
          ff[q] = feat[(size_t)(ent[q].x & 0x03FFFFFFu) * D + lane];
        #pragma unroll
        for (int q = 0; q < 16; ++q)
          acc[jj] += __uint_as_float(ent[q].y) * ff[q];
      }
      for (; p + 4 <= pe; p += 4) {
        uint2 ent[4];
        #pragma unroll
        for (int q = 0; q < 4; ++q) ent[q] = sdata[p + q];
        #pragma unroll
        for (int q = 0; q < 4; ++q)
          acc[jj] += __uint_as_float(ent[q].y) *
                     feat[(size_t)(ent[q].x & 0x03FFFFFFu) * D + lane];
      }
      for (; p < pe; ++p) {
        const uint2 en = sdata[p];
        acc[jj] += __uint_as_float(en.y) *
                   feat[(size_t)(en.x & 0x03FFFFFFu) * D + lane];
      }
    }
  }

  // epilogue: matvecs + tanh for this wave's 8 nodes
  #pragma unroll
  for (int jj = 0; jj < NB / 4; ++jj) {
    const int n = n0 + wv * (NB / 4) + jj;
    if (n >= N) break;
    const float f  = feat[(size_t)n * D + lane];
    const float nr = norm[n];
    float nf, lm = 0.0f;
    if (deg[jj] > 0) {
      const float pa = acc[jj];
      float a1 = 0.0f;
      #pragma unroll 8
      for (int k = 0; k < D; ++k) {
        const float fb = __shfl(f, k, 64);
        const float pb = __shfl(pa, k, 64);
        a1 += pb * W_rel[k * D + lane];
        lm += fb * loop_w[k * D + lane];
      }
      nf = a1 * nr;
    } else {
      #pragma unroll 8
      for (int k = 0; k < D; ++k) {
        const float fb = __shfl(f, k, 64);
        lm += fb * evolve_w[k * D + lane];
      }
      nf = f * nr;   // zero in-degree keeps old feat
    }
    out[(size_t)n * D + lane] = tanhf(nf + lm);
  }
}

extern "C" void kernel_launch(void* const* d_in, const int* in_sizes, int n_in,
                              void* d_out, int out_size, void* d_ws, size_t ws_size,
                              hipStream_t stream) {
  const float* feat     = (const float*)d_in[0];
  const float* norm     = (const float*)d_in[1];
  const int*   esrc     = (const int*)d_in[2];
  const int*   edst     = (const int*)d_in[3];
  // d_in[4] = etype: no-op permutation per the reference
  const float* W_rel    = (const float*)d_in[5];
  const float* lin_w    = (const float*)d_in[6];
  const float* lin_b    = (const float*)d_in[7];
  const float* loop_w   = (const float*)d_in[8];
  const float* evolve_w = (const float*)d_in[9];
  float* out = (float*)d_out;

  const int N = in_sizes[1];   // norm is [N]   (N <= 65536, src < 2^26)
  const int E = in_sizes[2];   // edge_src is [E]
  const int C = (N + NB - 1) >> SHIFT;   // 1563 for N=50000

  // workspace: s1[N] | s2[N] | bstart[CMAX] | gcur[CMAX] | ghist[CMAX] | ebuf[E]
  float* s1     = (float*)d_ws;
  float* s2     = s1 + N;
  int*   bstart = (int*)(s2 + N);
  int*   gcur   = bstart + CMAX;
  int*   ghist  = gcur + CMAX;
  uint2* ebuf   = (uint2*)(ghist + CMAX);

  const int eblocks = (E + CHUNK - 1) / CHUNK;   // 391 for E=1.6M

  hipMemsetAsync(ghist, 0, (size_t)C * sizeof(int), stream);
  precompute_att<<<512, 256, 0, stream>>>(feat, lin_w, lin_b, edst,
                                          s1, s2, ghist, C, N, E);
  scan_coarse<<<1, 1024, 0, stream>>>(ghist, bstart, gcur, C);
  coarse_scatter<<<eblocks, 256, 0, stream>>>(esrc, edst, s1, s2, gcur, ebuf, E, C);
  bucket_reduce<<<C, 256, 0, stream>>>(feat, norm, bstart, gcur, ebuf,
                                       W_rel, loop_w, evolve_w, out, N);
}